// Round 2
// baseline (321.689 us; speedup 1.0000x reference)
//
#include <hip/hip_runtime.h>
#include <hip/hip_bf16.h>

// Dims fixed by the reference
#define BB 8
#define NN 2048
#define DF 256
#define HH 64

using bf16x8 = __attribute__((ext_vector_type(8))) short;
using f32x4  = __attribute__((ext_vector_type(4))) float;
typedef unsigned short u16;

static __device__ __forceinline__ short bf_hi_bits(float v, float* hi_f) {
    __hip_bfloat16 h = __float2bfloat16(v);
    *hi_f = __bfloat162float(h);
    return __builtin_bit_cast(short, h);
}

// ---------------------------------------------------------------------------
// Kernel 0: pre-split W (fp32) into MFMA B-fragment order, split bf16 (hi,lo).
// B-operand layout (mfma_f32_16x16x32_bf16): lane l holds
// B[k = (l>>4)*8 + j][n = l&15]. Buffer: [kc(8)][ct(8)][p(hi/lo)][lane(64)][8]
// ct 0..3 -> Wq cols (ct&3)*16.., ct 4..7 -> Wk.
// Wsp lives at the START of the pi output buffer (temporal alias: written by
// this kernel, read by qk_mfma, overwritten later by attn_kernel -> safe on
// one stream). Total d_ws usage stays at the proven 8,388,608 bytes.
// ---------------------------------------------------------------------------
__global__ __launch_bounds__(64) void wprep_kernel(
    const float* __restrict__ Wq, const float* __restrict__ Wk,
    u16* __restrict__ Wsp)
{
    const int fid  = blockIdx.x;          // kc*8 + ct
    const int kc   = fid >> 3, ct = fid & 7;
    const int lane = threadIdx.x;
    const float* W = (ct < 4) ? Wq : Wk;
    const int col  = (ct & 3) * 16 + (lane & 15);
    const int krow = kc * 32 + (lane >> 4) * 8;
    bf16x8 hv, lv;
#pragma unroll
    for (int j = 0; j < 8; ++j) {
        float w = W[(size_t)(krow + j) * HH + col];
        float hf, d;
        hv[j] = bf_hi_bits(w, &hf);
        lv[j] = bf_hi_bits(w - hf, &d);
    }
    u16* dst = Wsp + (size_t)fid * 1024 + lane * 8;
    *(bf16x8*)dst         = hv;
    *(bf16x8*)(dst + 512) = lv;
}

// ---------------------------------------------------------------------------
// Kernel 1: Q/K projection via split-bf16 MFMA.
// C[16384 x 128] = F[16384 x 256] @ [Wq|Wk], 3 products (hh + hl + lh).
// One wave per block, 16 rows x 128 cols, grid 1024. log_eps * W[256][h]
// added exactly in fp32 at the epilogue; q scaled by 1/8; output split bf16.
// ---------------------------------------------------------------------------
__global__ __launch_bounds__(64) void qk_mfma_kernel(
    const float* __restrict__ f, const float* __restrict__ log_eps,
    const float* __restrict__ Wq, const float* __restrict__ Wk,
    const u16* __restrict__ Wsp,
    __hip_bfloat16* __restrict__ Qs, __hip_bfloat16* __restrict__ Ks)
{
    const int lane = threadIdx.x;
    const int l15  = lane & 15, quad = lane >> 4;
    const int row0 = blockIdx.x * 16;
    const int b    = row0 >> 11;          // 16-row blocks never straddle batch

    f32x4 acc[8] = {};
    const float* frow = f + (size_t)(row0 + l15) * DF + quad * 8;

#pragma unroll
    for (int kc = 0; kc < 8; ++kc) {
        // A-fragment: row = l15, k = quad*8 + j (fp32 -> split bf16)
        float4 a0 = *(const float4*)(frow + kc * 32);
        float4 a1 = *(const float4*)(frow + kc * 32 + 4);
        bf16x8 ah, al;
#pragma unroll
        for (int e = 0; e < 4; ++e) {
            float hf, d;
            float v0 = (&a0.x)[e], v1 = (&a1.x)[e];
            ah[e]     = bf_hi_bits(v0, &hf);
            al[e]     = bf_hi_bits(v0 - hf, &d);
            ah[e + 4] = bf_hi_bits(v1, &hf);
            al[e + 4] = bf_hi_bits(v1 - hf, &d);
        }
        const u16* wb = Wsp + (size_t)kc * 8192 + lane * 8;
#pragma unroll
        for (int ct = 0; ct < 8; ++ct) {
            bf16x8 bh = *(const bf16x8*)(wb + ct * 1024);
            bf16x8 bl = *(const bf16x8*)(wb + ct * 1024 + 512);
            acc[ct] = __builtin_amdgcn_mfma_f32_16x16x32_bf16(ah, bh, acc[ct], 0, 0, 0);
            acc[ct] = __builtin_amdgcn_mfma_f32_16x16x32_bf16(ah, bl, acc[ct], 0, 0, 0);
            acc[ct] = __builtin_amdgcn_mfma_f32_16x16x32_bf16(al, bh, acc[ct], 0, 0, 0);
        }
    }

    const float le = log_eps[b];
#pragma unroll
    for (int ct = 0; ct < 8; ++ct) {
        const int h = (ct & 3) * 16 + l15;
        const float wlast = (ct < 4 ? Wq : Wk)[DF * HH + h];
        __hip_bfloat16* out = (ct < 4) ? Qs : Ks;
        const float sc = (ct < 4) ? 0.125f : 1.0f;
#pragma unroll
        for (int r = 0; r < 4; ++r) {
            int bn = row0 + quad * 4 + r;     // C/D: col=l15, row=quad*4+r
            float v = (acc[ct][r] + le * wlast) * sc;
            __hip_bfloat16 hi = __float2bfloat16(v);
            __hip_bfloat16 lo = __float2bfloat16(v - __bfloat162float(hi));
            out[(size_t)bn * 128 + h]      = hi;
            out[(size_t)bn * 128 + 64 + h] = lo;
        }
    }
}

// ---------------------------------------------------------------------------
// Kernel 2: fused attention. Grid (64 strips, 4 chunks, 8 b) = 2048 blocks
// (4x the baseline's parallelism; baseline was occupancy-bound at 20%).
// Every block: pass 1 = full column sums over ALL 2048 rows for its 32-col
// strip (recomputed per chunk -- MFMA is ~12% util, recompute is free and
// removes the need for any cross-block scratch buffers). Chunk-0 blocks also
// accumulate sum_n exp*x and write y. Pass 2 = recompute logits for this
// block's 512-row chunk only and stream the pi write (the 134 MB floor).
// No workspace beyond Qs/Ks; no atomics to global; no extra barriers.
// ---------------------------------------------------------------------------
__global__ __launch_bounds__(256) void attn_kernel(
    const u16* __restrict__ Qs, const u16* __restrict__ Ks,
    const float* __restrict__ x, float* __restrict__ y, float* __restrict__ pi)
{
    __shared__ float cred[32];
    __shared__ float yred[4 * 2 * 16 * 3];

    const int tid   = threadIdx.x;
    const int strip = blockIdx.x;
    const int chunk = blockIdx.y;
    const int b     = blockIdx.z;
    const int m0    = strip * 32;
    const int wave  = tid >> 6;
    const int lane  = tid & 63;
    const int l15   = lane & 15;
    const int quad  = lane >> 4;
    const bool do_y = (chunk == 0);

    if (tid < 32) cred[tid] = 0.f;
    __syncthreads();

    // K strip B-fragments, resident all kernel
    bf16x8 bh[2][2], bl[2][2];
    {
        const u16* Kb = Ks + ((size_t)b * NN + m0) * 128;
#pragma unroll
        for (int ct = 0; ct < 2; ++ct) {
            const u16* kr = Kb + (size_t)(ct * 16 + l15) * 128;
#pragma unroll
            for (int ks = 0; ks < 2; ++ks) {
                int k0 = ks * 32 + quad * 8;
                bh[ct][ks] = *(const bf16x8*)(kr + k0);
                bl[ct][ks] = *(const bf16x8*)(kr + 64 + k0);
            }
        }
    }

    const u16*  Qb = Qs + (size_t)b * NN * 128;
    const float* xb = x + (size_t)b * NN * 3;
    float cs0 = 0.f, cs1 = 0.f;
    float yacc[2][3] = {{0.f, 0.f, 0.f}, {0.f, 0.f, 0.f}};

    // ---- Pass 1: full column sums (all 2048 rows); chunk-0 also y-acc ----
    for (int rt = 0; rt < 16; ++rt) {
#pragma unroll
        for (int sr = 0; sr < 2; ++sr) {
            const int row0 = rt * 128 + wave * 32 + sr * 16;
            const u16* qr = Qb + (size_t)(row0 + l15) * 128;
            bf16x8 ah[2], al[2];
#pragma unroll
            for (int ks = 0; ks < 2; ++ks) {
                int k0 = ks * 32 + quad * 8;
                ah[ks] = *(const bf16x8*)(qr + k0);
                al[ks] = *(const bf16x8*)(qr + 64 + k0);
            }
            float xv[4][3];
            if (do_y) {
#pragma unroll
                for (int r = 0; r < 4; ++r) {
                    int row = row0 + quad * 4 + r;
                    xv[r][0] = xb[row * 3 + 0];
                    xv[r][1] = xb[row * 3 + 1];
                    xv[r][2] = xb[row * 3 + 2];
                }
            }
#pragma unroll
            for (int ct = 0; ct < 2; ++ct) {
                f32x4 acc = {0.f, 0.f, 0.f, 0.f};
#pragma unroll
                for (int ks = 0; ks < 2; ++ks) {
                    acc = __builtin_amdgcn_mfma_f32_16x16x32_bf16(ah[ks], bh[ct][ks], acc, 0, 0, 0);
                    acc = __builtin_amdgcn_mfma_f32_16x16x32_bf16(ah[ks], bl[ct][ks], acc, 0, 0, 0);
                    acc = __builtin_amdgcn_mfma_f32_16x16x32_bf16(al[ks], bh[ct][ks], acc, 0, 0, 0);
                }
                float s = 0.f;
#pragma unroll
                for (int r = 0; r < 4; ++r) {
                    float v = __expf(acc[r]);
                    s += v;
                    if (do_y) {
                        yacc[ct][0] = fmaf(v, xv[r][0], yacc[ct][0]);
                        yacc[ct][1] = fmaf(v, xv[r][1], yacc[ct][1]);
                        yacc[ct][2] = fmaf(v, xv[r][2], yacc[ct][2]);
                    }
                }
                s += __shfl_xor(s, 16);
                s += __shfl_xor(s, 32);
                if (ct == 0) cs0 += s; else cs1 += s;
            }
        }
    }

    if (quad == 0) {
        atomicAdd(&cred[l15],      cs0);
        atomicAdd(&cred[16 + l15], cs1);
    }
    if (do_y) {
#pragma unroll
        for (int ct = 0; ct < 2; ++ct)
#pragma unroll
            for (int d = 0; d < 3; ++d) {
                yacc[ct][d] += __shfl_xor(yacc[ct][d], 16);
                yacc[ct][d] += __shfl_xor(yacc[ct][d], 32);
            }
        if (quad == 0) {
#pragma unroll
            for (int ct = 0; ct < 2; ++ct)
#pragma unroll
                for (int d = 0; d < 3; ++d)
                    yred[((wave * 2 + ct) * 16 + l15) * 3 + d] = yacc[ct][d];
        }
    }
    __syncthreads();

    if (do_y && tid < 96) {                  // y[m,d] = (sum exp*x) / colsum
        int c = tid / 3, d = tid - c * 3;
        int ct = c >> 4, cl = c & 15;
        float s = 0.f;
#pragma unroll
        for (int w = 0; w < 4; ++w)
            s += yred[((w * 2 + ct) * 16 + cl) * 3 + d];
        y[((size_t)b * NN + m0 + c) * 3 + d] = s / cred[c];
    }

    const float invN = 1.0f / (float)NN;
    const float iv0  = invN / cred[l15];
    const float iv1  = invN / cred[16 + l15];
    float* pib = pi + (size_t)b * NN * NN + m0;
    const int n0 = chunk * 512;

    // ---- Pass 2: recompute this chunk's 512 rows, write pi ----
    for (int rt = 0; rt < 4; ++rt) {
#pragma unroll
        for (int sr = 0; sr < 2; ++sr) {
            const int row0 = n0 + rt * 128 + wave * 32 + sr * 16;
            const u16* qr = Qb + (size_t)(row0 + l15) * 128;
            bf16x8 ah[2], al[2];
#pragma unroll
            for (int ks = 0; ks < 2; ++ks) {
                int k0 = ks * 32 + quad * 8;
                ah[ks] = *(const bf16x8*)(qr + k0);
                al[ks] = *(const bf16x8*)(qr + 64 + k0);
            }
#pragma unroll
            for (int ct = 0; ct < 2; ++ct) {
                f32x4 acc = {0.f, 0.f, 0.f, 0.f};
#pragma unroll
                for (int ks = 0; ks < 2; ++ks) {
                    acc = __builtin_amdgcn_mfma_f32_16x16x32_bf16(ah[ks], bh[ct][ks], acc, 0, 0, 0);
                    acc = __builtin_amdgcn_mfma_f32_16x16x32_bf16(ah[ks], bl[ct][ks], acc, 0, 0, 0);
                    acc = __builtin_amdgcn_mfma_f32_16x16x32_bf16(al[ks], bh[ct][ks], acc, 0, 0, 0);
                }
                const float iv = (ct == 0) ? iv0 : iv1;
                float* op = pib + (size_t)(row0 + quad * 4) * NN + ct * 16 + l15;
#pragma unroll
                for (int r = 0; r < 4; ++r)
                    op[(size_t)r * NN] = __expf(acc[r]) * iv;
            }
        }
    }
}

// ---------------------------------------------------------------------------
extern "C" void kernel_launch(void* const* d_in, const int* in_sizes, int n_in,
                              void* d_out, int out_size, void* d_ws, size_t ws_size,
                              hipStream_t stream) {
    const float* f  = (const float*)d_in[0];
    const float* x  = (const float*)d_in[1];
    const float* le = (const float*)d_in[2];
    const float* Wq = (const float*)d_in[3];
    const float* Wk = (const float*)d_in[4];

    float* y  = (float*)d_out;                       // (B, N, 3)
    float* pi = (float*)d_out + (size_t)BB * NN * 3; // (B, N, N)

    // Workspace: exactly the proven 8 MB (split-bf16 Q and K). All other
    // scratch (the 128 KB W-fragment table) temporally aliases the pi output
    // buffer: wprep writes it, qk_mfma reads it, attn_kernel overwrites it.
    __hip_bfloat16* Qs = (__hip_bfloat16*)d_ws;      // 4 MB
    __hip_bfloat16* Ks = Qs + (size_t)BB * NN * 128; // 4 MB
    u16* Wsp = (u16*)pi;                             // 128 KB, stream-ordered alias

    wprep_kernel<<<dim3(64), 64, 0, stream>>>(Wq, Wk, Wsp);
    qk_mfma_kernel<<<dim3(BB * NN / 16), 64, 0, stream>>>(f, le, Wq, Wk, Wsp, Qs, Ks);
    attn_kernel<<<dim3(64, 4, BB), 256, 0, stream>>>((const u16*)Qs, (const u16*)Ks,
                                                     x, y, pi);
}